// Round 8
// baseline (218.426 us; speedup 1.0000x reference)
//
#include <hip/hip_runtime.h>
#include <hip/hip_bf16.h>

typedef unsigned short u16;
typedef __attribute__((ext_vector_type(8))) short short8;   // 8 bf16 (4 VGPRs)
typedef __attribute__((ext_vector_type(4))) float f32x4;

#define NN 9
#define DX 128
#define KP 64
#define LL 32
#define NALL 100000
#define BMAX 8192
#define NBM 16   // b's per k_main block (16 waves of 1024-thread block)
#define NBP 64   // proto blocks in k_lin, 1 prototype per block
#define HXR 136  // padded hS row stride (u16) -> bank-rotating for row-stride reads
#define WSTR 3584 // per-wave LDS region stride (bytes)

#define MFMA(a, b, c) __builtin_amdgcn_mfma_f32_16x16x32_bf16(a, b, c, 0, 0, 0)
#define WFENCE() __threadfence_block()

// ---------- cross-kernel tables ----------
__device__ __align__(16) float g_tns[LL * NN];        // normalized theta_s [l][j]
__device__ __align__(16) float g_hprn[KP];            // ||h_proto_root||^2 [k]
__device__ __align__(16) float g_hpt[32 * KP];        // hp^T [j][k]
__device__ __align__(16) float g_rpst[NN * KP];       // sorted proto_rad [m][k]
__device__ __align__(16) float g_prm[416];            // xlb|xlg|xlbt|slg|slb packed f32
__device__ __align__(16) u16   g_hroot[BMAX * DX];    // root LN'd h rows, bf16
__device__ __align__(16) u16   g_hpool[BMAX * DX];    // pooled neighbor h, bf16
__device__ __align__(16) float g_hrn[BMAX];           // ||h_root||^2 per b
__device__ __align__(16) u16   g_Cf[BMAX * 576];      // feature sort frags [wgt|-2wv] per b
__device__ __align__(16) u16   g_Cs[BMAX * 576];      // structural sort frags per b
__device__ __align__(16) float g_drad[BMAX * 64];     // radial distance per (b,k)
__device__ __align__(16) float g_t1x[BMAX];           // t1 feature
__device__ __align__(16) float g_t1s[BMAX];           // t1 structural
// MFMA fragment-packed B tables (bf16)
__device__ __align__(16) u16   g_pW[16384];           // x_lin_w: K=128, N=128 (L1-resident)
__device__ __align__(16) u16   g_pBt[4096];           // tnx:  K=128, N=32
__device__ __align__(16) u16   g_pBr[8192];           // hprt: K=128, N=64
__device__ __align__(16) u16   g_pBx[36864];          // sw feat [pf^2|pf]: K=576, N=64
__device__ __align__(16) u16   g_pBs[36864];          // sw str  [qf^2|qf]: K=576, N=64
__device__ __align__(16) u16   g_pAn[4096];           // an_w1: K=128, N=32
__device__ __align__(16) u16   g_pWn[4096];           // wn_w1[:128]: K=128, N=32

__device__ __forceinline__ float bf2f(u16 u) {
    union { unsigned u; float f; } v; v.u = ((unsigned)u) << 16; return v.f;
}
__device__ __forceinline__ u16 f2bf(float f) {
    __hip_bfloat16 h = __float2bfloat16(f);
    union { __hip_bfloat16 h; u16 u; } v; v.h = h; return v.u;
}
__device__ __forceinline__ float ldv(const void* p, long i, int f32) {
    return f32 ? ((const float*)p)[i] : bf2f(((const u16*)p)[i]);
}
__device__ __forceinline__ float sigmoidf(float x) { return 1.f / (1.f + expf(-x)); }

__device__ __forceinline__ int bfrag_idx(int ksteps, int ncol, int kd) {
    int ntile = ncol >> 4, n = ncol & 15;
    int kstep = kd >> 5, quad = (kd >> 3) & 3, j = kd & 7;
    return ((ntile * ksteps + kstep) * 64 + quad * 16 + n) * 8 + j;
}

__device__ __forceinline__ void rank9(const float* v, int* r) {
#pragma unroll
    for (int m = 0; m < 9; m++) {
        int rk = 0;
#pragma unroll
        for (int n = 0; n < 9; n++)
            rk += (v[n] < v[m]) || (v[n] == v[m] && n < m);
        r[m] = rk;
    }
}

// ---------------- kernel 0: one-time packing ----------------
__global__ __launch_bounds__(256) void k_pack(
    const void* xlw, const void* theta_x, const void* theta_s,
    const void* an_w1, const void* wn_w1, const void* proto_rad,
    const void* xlb, const void* xlg, const void* xlbt,
    const void* slg, const void* slb) {
    int t = threadIdx.x;
    const int f32 = (((const u16*)xlg)[0] == 0);
    if (blockIdx.x == 0) {
        for (int i = t; i < 16384; i += 256) {
            int c = i >> 7, d = i & 127;
            g_pW[bfrag_idx(4, d, c)] = f2bf(ldv(xlw, i, f32));
        }
    } else if (blockIdx.x == 1) {
        if (t < 32) {
            float s = 0;
            for (int d = 0; d < 128; d++) { float v = ldv(theta_x, t * 128 + d, f32); s = fmaf(v, v, s); }
            float inv = 1.f / sqrtf(s);
            for (int d = 0; d < 128; d++)
                g_pBt[bfrag_idx(4, t, d)] = f2bf(ldv(theta_x, t * 128 + d, f32) * inv);
        } else if (t < 64) {
            int l = t - 32;
            float s = 0;
            for (int j = 0; j < 9; j++) { float v = ldv(theta_s, l * 9 + j, f32); s = fmaf(v, v, s); }
            float inv = 1.f / sqrtf(s);
            for (int j = 0; j < 9; j++) g_tns[l * 9 + j] = ldv(theta_s, l * 9 + j, f32) * inv;
        } else if (t < 128) {
            int k = t - 64;
            float v[9]; int r[9];
#pragma unroll
            for (int m = 0; m < 9; m++) v[m] = ldv(proto_rad, k * 9 + m, f32);
            rank9(v, r);
#pragma unroll
            for (int m = 0; m < 9; m++) g_rpst[r[m] * 64 + k] = v[m];
        }
    } else {
        for (int i = t; i < 4096; i += 256) {
            int d = i >> 5, j = i & 31;
            g_pAn[bfrag_idx(4, j, d)] = f2bf(ldv(an_w1, i, f32));
            g_pWn[bfrag_idx(4, j, d)] = f2bf(ldv(wn_w1, i, f32));
        }
        for (int i = t; i < 402; i += 256) {
            float v;
            if (i < 128)      v = ldv(xlb,  i,       f32);
            else if (i < 256) v = ldv(xlg,  i - 128, f32);
            else if (i < 384) v = ldv(xlbt, i - 256, f32);
            else if (i < 393) v = ldv(slg,  i - 384, f32);
            else              v = ldv(slb,  i - 393, f32);
            g_prm[i] = v;
        }
    }
}

// ---------------- kernel 1: wave-autonomous per-b pipeline; proto blocks run proto chain ----
// Batch path: 1 wave = 1 b, zero block barriers. pb transposes done via shuffles (no LDS
// round-trips); params via g_prm + shuffle broadcast; adj row via vector loads.
__global__ __launch_bounds__(256, 5) void k_lin(
    const void* adj, const void* feat, const int* idxs,
    const void* proto_root, const void* proto_neigh,
    const void* xlb, const void* xlg, const void* xlbt,
    const void* slg, const void* slb, const void* wn_w1,
    const void* proto_dn, int B) {
    __shared__ __align__(16) char sm[4 * WSTR];

    int t = threadIdx.x, lane = t & 63, w = t >> 6;
    const int f32 = (((const u16*)xlg)[0] == 0);
    int fm = lane & 15, quad = lane >> 4;
    bool isProto = (blockIdx.x < (unsigned)NBP);

    if (!isProto) {
        // ---- per-wave LDS region ----
        u16*   hSw = (u16*)(sm + w * WSTR);              // [10][HXR] 2720B
        float* dfw = (float*)(sm + w * WSTR + 2720);     // [10][10]
        float* stw = (float*)(sm + w * WSTR + 3120);     // [81]
        float* rbw = (float*)(sm + w * WSTR + 3456);     // [9]
        float* wrw = (float*)(sm + w * WSTR + 3496);     // [9]

        int bw = (blockIdx.x - NBP) * 4 + w;
        if (bw >= B) return;   // safe: no barriers in this path

        // ---- param rows (6 loads; extracted by shuffle later) ----
        float r0 = g_prm[lane],       r1 = g_prm[64 + lane];
        float r2 = g_prm[128 + lane], r3 = g_prm[192 + lane];
        float r4 = g_prm[256 + lane], r5 = g_prm[320 + lane];

        // ---- masks ----
        bool valid = false;
        if (lane < 10) {
            int id = idxs[bw * 10 + lane];
            valid = (lane == 0) || (id != NALL);
        }
        unsigned long long mb = __ballot(valid);
        float inv = 1.f / ((float)__popcll(mb & 0x3FEull) + 1e-9f);

        // ---- issue feature gather for this b's 10 rows ----
        bool azero = true; long aoff = 0;
        if (fm < 10) {
            int id2 = idxs[bw * 10 + fm];
            if (id2 != NALL) { azero = false; aoff = (long)id2 * 128; }
        }
        short8 af[4];
#pragma unroll
        for (int ks = 0; ks < 4; ks++) af[ks] = (short8){0, 0, 0, 0, 0, 0, 0, 0};
        if (!azero) {
            if (f32) {
#pragma unroll
                for (int ks = 0; ks < 4; ks++) {
                    const f32x4* src = (const f32x4*)((const float*)feat + aoff + ks * 32 + quad * 8);
                    f32x4 v0 = src[0], v1 = src[1];
                    u16* ap = (u16*)&af[ks];
#pragma unroll
                    for (int j = 0; j < 4; j++) { ap[j] = f2bf(v0[j]); ap[4 + j] = f2bf(v1[j]); }
                }
            } else {
#pragma unroll
                for (int ks = 0; ks < 4; ks++)
                    af[ks] = *(const short8*)((const u16*)feat + aoff + ks * 32 + quad * 8);
            }
        }

        // ---- BFS (hides gather latency; adj row via 5 vector loads) ----
        unsigned rowbits = 0;
        if (lane < 10) {
            float ev[10];
            if (f32) {
#pragma unroll
                for (int k = 0; k < 5; k++) {
                    float2 p = ((const float2*)adj)[(long)bw * 50 + lane * 5 + k];
                    ev[2 * k] = p.x; ev[2 * k + 1] = p.y;
                }
            } else {
#pragma unroll
                for (int k = 0; k < 5; k++) {
                    unsigned p = ((const unsigned*)adj)[(long)bw * 50 + lane * 5 + k];
                    ev[2 * k] = bf2f((u16)p); ev[2 * k + 1] = bf2f((u16)(p >> 16));
                }
            }
#pragma unroll
            for (int j = 0; j < 10; j++)
                if (ev[j] > 1e-5f) rowbits |= 1u << j;
        }
        int dl[10];
#pragma unroll
        for (int j = 0; j < 10; j++) dl[j] = (j == lane) ? 0 : (((rowbits >> j) & 1) ? 1 : 10);
        unsigned reach = (lane < 10) ? (rowbits | (1u << lane)) : 0u;
        for (int s = 2; s <= 9; s++) {
            unsigned nr = reach;
#pragma unroll
            for (int j = 0; j < 10; j++) {
                unsigned rj = __shfl(rowbits, j);
                if ((reach >> j) & 1) nr |= rj;
            }
            unsigned add = nr & ~reach;
#pragma unroll
            for (int j = 0; j < 10; j++) if ((add >> j) & 1) dl[j] = s;
            reach = nr;
            if (__all(add == 0)) break;
        }
        if (lane < 10) {
            int mi = (int)((mb >> lane) & 1);
#pragma unroll
            for (int j = 0; j < 10; j++) {
                int mj = (int)((mb >> j) & 1);
                dfw[lane * 10 + j] = (mi && mj) ? (float)dl[j] * 0.1f : 1.0f;
            }
        }
        {   // row-0 distances: broadcast then 9-lane rank
            float v[9];
#pragma unroll
            for (int m = 0; m < 9; m++) {
                float vm = ((mb >> (1 + m)) & 1) ? (float)dl[1 + m] * 0.1f : 1.0f;
                v[m] = __shfl(vm, 0);
            }
            if (lane < 9) {
                float mine = v[0];
#pragma unroll
                for (int m = 1; m < 9; m++) if (lane == m) mine = v[m];
                int rk = 0;
#pragma unroll
                for (int n = 0; n < 9; n++) rk += (v[n] < mine) || (v[n] == mine && n < lane);
                rbw[rk] = mine;
                wrw[rk] = (((mb >> (1 + lane)) & 1) ? 1.f : 0.f) * inv;
            }
        }

        // ---- lin-MFMA + LN -> hSw (params via shuffle from r0..r5) ----
        {
            float bias8[8], gg8[8], bb8[8];
#pragma unroll
            for (int nt = 0; nt < 8; nt++) {
                int src = (nt * 16 + fm) & 63;
                bias8[nt] = __shfl(nt < 4 ? r0 : r1, src);
                gg8[nt]   = __shfl(nt < 4 ? r2 : r3, src);
                bb8[nt]   = __shfl(nt < 4 ? r4 : r5, src);
            }
            f32x4 acc[8];
#pragma unroll
            for (int nt = 0; nt < 8; nt++) acc[nt] = (f32x4){0.f, 0.f, 0.f, 0.f};
#pragma unroll
            for (int ks = 0; ks < 4; ks++) {
#pragma unroll
                for (int nt = 0; nt < 8; nt++) {
                    short8 bf = *(const short8*)(g_pW + ((nt * 4 + ks) * 64 + lane) * 8);
                    acc[nt] = MFMA(af[ks], bf, acc[nt]);
                }
            }
#pragma unroll
            for (int reg = 0; reg < 4; reg++) {
                float s = 0, q = 0;
#pragma unroll
                for (int nt = 0; nt < 8; nt++) {
                    float v = acc[nt][reg] + bias8[nt];
                    s += v; q = fmaf(v, v, q);
                }
#pragma unroll
                for (int m = 1; m < 16; m <<= 1) { s += __shfl_xor(s, m); q += __shfl_xor(q, m); }
                float mu = s * (1.f / 128.f);
                float var = fmaxf(q * (1.f / 128.f) - mu * mu, 0.f);
                float rs = rsqrtf(var + 1e-5f);
                int rowD = quad * 4 + reg;
                if (rowD < 10) {
#pragma unroll
                    for (int nt = 0; nt < 8; nt++) {
                        float val = (acc[nt][reg] + bias8[nt] - mu) * rs * gg8[nt] + bb8[nt];
                        hSw[rowD * HXR + nt * 16 + fm] = f2bf(val);
                    }
                }
            }
        }
        WFENCE();   // hSw ready (intra-wave)

        // ---- hroot copy + hrn + pool ----
        if (lane < 16)
            ((short8*)(g_hroot + (long)bw * 128))[lane] = ((const short8*)hSw)[lane];
        {
            float v0 = bf2f(hSw[lane]), v1 = bf2f(hSw[64 + lane]);
            float q = v0 * v0 + v1 * v1;
#pragma unroll
            for (int m = 32; m >= 1; m >>= 1) q += __shfl_xor(q, m);
            if (lane == 0) g_hrn[bw] = q;
        }
        {
            float a0 = 0, a1 = 0;
            int c0 = lane * 2, c1 = lane * 2 + 1;
#pragma unroll
            for (int m = 0; m < 9; m++) {
                float msk = ((mb >> (1 + m)) & 1) ? 1.f : 0.f;
                a0 = fmaf(bf2f(hSw[(1 + m) * HXR + c0]), msk, a0);
                a1 = fmaf(bf2f(hSw[(1 + m) * HXR + c1]), msk, a1);
            }
            unsigned pk = (unsigned)f2bf(a0 * inv) | ((unsigned)f2bf(a1 * inv) << 16);
            ((unsigned*)(g_hpool + (long)bw * 128))[lane] = pk;
        }

        // ---- feature projections MFMA; rank reads accs via shuffle transpose ----
        {
            f32x4 acc0 = {0.f, 0.f, 0.f, 0.f}, acc1 = {0.f, 0.f, 0.f, 0.f};
            const u16* arow = hSw + (1 + fm) * HXR;
#pragma unroll
            for (int ks = 0; ks < 4; ks++) {
                short8 afn = {0, 0, 0, 0, 0, 0, 0, 0};
                if (fm < 9) afn = *(const short8*)(arow + ks * 32 + quad * 8);
                short8 b0 = *(const short8*)(g_pBt + ((0 * 4 + ks) * 64 + lane) * 8);
                short8 b1 = *(const short8*)(g_pBt + ((1 * 4 + ks) * 64 + lane) * 8);
                acc0 = MFMA(afn, b0, acc0);
                acc1 = MFMA(afn, b1, acc1);
            }
            // shuffle-transpose: v[m] = value(row m, col lane&31)
            float v[9];
#pragma unroll
            for (int m = 0; m < 9; m++) {
                int src = (m >> 2) * 16 + (lane & 15);
                float s0 = __shfl(acc0[m & 3], src);
                float s1 = __shfl(acc1[m & 3], src);
                v[m] = ((lane & 31) < 16) ? s0 : s1;
            }
            float t1 = 0;
            if (lane < 32) {
                int r[9];
                rank9(v, r);
#pragma unroll
                for (int m = 0; m < 9; m++) {
                    float wgt = (((mb >> (1 + m)) & 1) ? 1.f : 0.f) * inv;
                    int slot = lane * 9 + r[m];
                    g_Cf[(long)bw * 576 + slot]       = f2bf(wgt);
                    g_Cf[(long)bw * 576 + 288 + slot] = f2bf(-2.f * wgt * v[m]);
                    t1 = fmaf(wgt * v[m], v[m], t1);
                }
            }
#pragma unroll
            for (int m = 16; m >= 1; m >>= 1) t1 += __shfl_xor(t1, m);
            if (lane == 0) g_t1x[bw] = t1;
        }

        // ---- hst column sort -> stw ----
        if (lane < 9) {
            float v[9]; int r[9];
#pragma unroll
            for (int i = 0; i < 9; i++) v[i] = dfw[(1 + i) * 10 + 1 + lane];
            rank9(v, r);
#pragma unroll
            for (int i = 0; i < 9; i++) stw[r[i] * 9 + lane] = v[i];
        }
        WFENCE();
        // ---- LN rows of stw in place ----
        if (lane < 9) {
            float vv[9];
#pragma unroll
            for (int j = 0; j < 9; j++) vv[j] = stw[lane * 9 + j];
            float mu = 0;
#pragma unroll
            for (int j = 0; j < 9; j++) mu += vv[j];
            mu *= (1.f / 9.f);
            float var = 0;
#pragma unroll
            for (int j = 0; j < 9; j++) { float d0 = vv[j] - mu; var = fmaf(d0, d0, var); }
            var *= (1.f / 9.f);
            float rs = rsqrtf(var + 1e-5f);
#pragma unroll
            for (int j = 0; j < 9; j++)
                stw[lane * 9 + j] = (vv[j] - mu) * rs * g_prm[384 + j] + g_prm[393 + j];
        }
        WFENCE();
        // ---- structural projections in registers; rank via 4 shuffles ----
        {
            int l = lane & 31;
            float pa[5];
#pragma unroll
            for (int mm = 0; mm < 5; mm++) {
                int m = (lane < 32) ? mm : mm + 5;
                float a = 0;
                if (m < 9) {
#pragma unroll
                    for (int j = 0; j < 9; j++) a = fmaf(stw[m * 9 + j], g_tns[l * 9 + j], a);
                }
                pa[mm] = a;
            }
            float v[9];
#pragma unroll
            for (int m = 0; m < 5; m++) v[m] = pa[m];
#pragma unroll
            for (int m = 5; m < 9; m++) v[m] = __shfl(pa[m - 5], (lane & 31) + 32);
            float t1 = 0;
            if (lane < 32) {
                int r[9];
                rank9(v, r);
#pragma unroll
                for (int m = 0; m < 9; m++) {
                    float wgt = (((mb >> (1 + m)) & 1) ? 1.f : 0.f) * inv;
                    int slot = lane * 9 + r[m];
                    g_Cs[(long)bw * 576 + slot]       = f2bf(wgt);
                    g_Cs[(long)bw * 576 + 288 + slot] = f2bf(-2.f * wgt * v[m]);
                    t1 = fmaf(wgt * v[m], v[m], t1);
                }
            }
#pragma unroll
            for (int m = 16; m >= 1; m >>= 1) t1 += __shfl_xor(t1, m);
            if (lane == 0) g_t1s[bw] = t1;
        }
        // ---- drad ----
        {
            float a = 0;
#pragma unroll
            for (int m = 0; m < 9; m++) {
                float d0 = rbw[m] - g_rpst[m * 64 + lane];
                a = fmaf(d0 * d0, wrw[m], a);
            }
            g_drad[(long)bw * 64 + lane] = a;
        }
        return;
    }

    // ================= proto chain (1 prototype per block) =================
    u16*   hXpb = (u16*)sm;              // [10][128]
    float* pbX  = (float*)(sm + 2560);   // [9][32]
    float* Cm   = (float*)(sm + 3712);   // [81]
    float* hsnP = (float*)(sm + 4048);   // [81]
    int kb = blockIdx.x;

    if (w == 0) {   // lin+LN for the 10 proto rows (B-frags from g_pW, L1-hot)
        const void* abuf; long aoff;
        if (fm < 9) { abuf = proto_neigh; aoff = (long)(kb * 9 + fm) * 128; }
        else        { abuf = proto_root;  aoff = (long)kb * 128; }
        bool arow = (fm < 10);
        short8 af[4];
#pragma unroll
        for (int ks = 0; ks < 4; ks++) af[ks] = (short8){0, 0, 0, 0, 0, 0, 0, 0};
        if (arow) {
            if (f32) {
#pragma unroll
                for (int ks = 0; ks < 4; ks++) {
                    const f32x4* src = (const f32x4*)((const float*)abuf + aoff + ks * 32 + quad * 8);
                    f32x4 v0 = src[0], v1 = src[1];
                    u16* ap = (u16*)&af[ks];
#pragma unroll
                    for (int j = 0; j < 4; j++) { ap[j] = f2bf(v0[j]); ap[4 + j] = f2bf(v1[j]); }
                }
            } else {
#pragma unroll
                for (int ks = 0; ks < 4; ks++)
                    af[ks] = *(const short8*)((const u16*)abuf + aoff + ks * 32 + quad * 8);
            }
        }
        float bias8[8], gg8[8], bb8[8];
#pragma unroll
        for (int nt = 0; nt < 8; nt++) {
            int col = nt * 16 + fm;
            bias8[nt] = ldv(xlb, col, f32);
            gg8[nt]   = ldv(xlg, col, f32);
            bb8[nt]   = ldv(xlbt, col, f32);
        }
        f32x4 acc[8];
#pragma unroll
        for (int nt = 0; nt < 8; nt++) acc[nt] = (f32x4){0.f, 0.f, 0.f, 0.f};
#pragma unroll
        for (int ks = 0; ks < 4; ks++) {
#pragma unroll
            for (int nt = 0; nt < 8; nt++) {
                short8 bf = *(const short8*)(g_pW + ((nt * 4 + ks) * 64 + lane) * 8);
                acc[nt] = MFMA(af[ks], bf, acc[nt]);
            }
        }
#pragma unroll
        for (int reg = 0; reg < 4; reg++) {
            float s = 0, q = 0;
#pragma unroll
            for (int nt = 0; nt < 8; nt++) {
                float v = acc[nt][reg] + bias8[nt];
                s += v; q = fmaf(v, v, q);
            }
#pragma unroll
            for (int m = 1; m < 16; m <<= 1) { s += __shfl_xor(s, m); q += __shfl_xor(q, m); }
            float mu = s * (1.f / 128.f);
            float var = fmaxf(q * (1.f / 128.f) - mu * mu, 0.f);
            float rs = rsqrtf(var + 1e-5f);
            int rowD = quad * 4 + reg;
            if (rowD < 10) {
#pragma unroll
                for (int nt = 0; nt < 8; nt++) {
                    float val = (acc[nt][reg] + bias8[nt] - mu) * rs * gg8[nt] + bb8[nt];
                    hXpb[rowD * 128 + nt * 16 + fm] = f2bf(val);
                }
            }
        }
    }
    __syncthreads();   // hXpb ready

    for (int i = t; i < 128; i += 256)
        g_pBr[bfrag_idx(4, kb, i)] = hXpb[1152 + i];
    if (w == 0) {
        float v0 = bf2f(hXpb[1152 + lane]);
        float v1 = bf2f(hXpb[1216 + lane]);
        float q = v0 * v0 + v1 * v1;
#pragma unroll
        for (int m = 32; m >= 1; m >>= 1) q += __shfl_xor(q, m);
        if (lane == 0) g_hprn[kb] = q;
    }
    {   // hpt: 256 threads = 32 j's x 8 segments of 16 d's, shuffle-reduce
        int j = t >> 3, sub = t & 7;
        float a = 0;
#pragma unroll
        for (int dd = 0; dd < 16; dd++) {
            int d = sub * 16 + dd;
            a = fmaf(bf2f(hXpb[1152 + d]), ldv(wn_w1, (128 + d) * 32 + j, f32), a);
        }
        a += __shfl_xor(a, 1);
        a += __shfl_xor(a, 2);
        a += __shfl_xor(a, 4);
        if (sub == 0) g_hpt[j * 64 + kb] = a;
    }
    if (w == 0) {
        f32x4 acc0 = {0.f, 0.f, 0.f, 0.f}, acc1 = {0.f, 0.f, 0.f, 0.f};
        const u16* arow2 = hXpb + fm * 128;
#pragma unroll
        for (int ks = 0; ks < 4; ks++) {
            short8 afp = {0, 0, 0, 0, 0, 0, 0, 0};
            if (fm < 9) afp = *(const short8*)(arow2 + ks * 32 + quad * 8);
            short8 b0 = *(const short8*)(g_pBt + ((0 * 4 + ks) * 64 + lane) * 8);
            short8 b1 = *(const short8*)(g_pBt + ((1 * 4 + ks) * 64 + lane) * 8);
            acc0 = MFMA(afp, b0, acc0);
            acc1 = MFMA(afp, b1, acc1);
        }
#pragma unroll
        for (int reg = 0; reg < 4; reg++) {
            int row = quad * 4 + reg;
            if (row < 9) {
                pbX[row * 32 + fm]      = acc0[reg];
                pbX[row * 32 + 16 + fm] = acc1[reg];
            }
        }
    }
    for (int i = t; i < 81; i += 256) {
        int ii = i / 9, jj = i % 9; float v = 0.f;
        if (ii != jj) {
            int a = (ii < jj) ? ii : jj, b2 = (ii < jj) ? jj : ii;
            int p = a * 8 - a * (a - 1) / 2 + (b2 - a - 1);
            v = sigmoidf(ldv(proto_dn, p * 64 + kb, f32));
        }
        Cm[i] = v;
    }
    __syncthreads();
    if (t < 32) {
        float v[9]; int r[9];
#pragma unroll
        for (int m = 0; m < 9; m++) v[m] = pbX[m * 32 + t];
        rank9(v, r);
#pragma unroll
        for (int m = 0; m < 9; m++) {
            int kd = t * 9 + r[m];
            g_pBx[bfrag_idx(18, kb, kd)]       = f2bf(v[m] * v[m]);
            g_pBx[bfrag_idx(18, kb, 288 + kd)] = f2bf(v[m]);
        }
    }
    if (t >= 64 && t < 73) {
        int col = t - 64;
        float v[9]; int r[9];
#pragma unroll
        for (int j = 0; j < 9; j++) v[j] = Cm[j * 9 + col];
        rank9(v, r);
#pragma unroll
        for (int j = 0; j < 9; j++) Cm[r[j] * 9 + col] = v[j];
    }
    __syncthreads();
    if (t < 9) {
        float mu = 0;
#pragma unroll
        for (int j = 0; j < 9; j++) mu += Cm[t * 9 + j];
        mu *= (1.f / 9.f);
        float var = 0;
#pragma unroll
        for (int j = 0; j < 9; j++) { float d0 = Cm[t * 9 + j] - mu; var = fmaf(d0, d0, var); }
        var *= (1.f / 9.f);
        float rs = rsqrtf(var + 1e-5f);
#pragma unroll
        for (int j = 0; j < 9; j++)
            hsnP[t * 9 + j] = (Cm[t * 9 + j] - mu) * rs * ldv(slg, j, f32) + ldv(slb, j, f32);
    }
    __syncthreads();
    if (t < 32) {
#pragma unroll
        for (int m = 0; m < 9; m++) {
            float a = 0;
#pragma unroll
            for (int j = 0; j < 9; j++) a = fmaf(hsnP[m * 9 + j], g_tns[t * 9 + j], a);
            pbX[m * 32 + t] = a;
        }
    }
    __syncthreads();
    if (t < 32) {
        float v[9]; int r[9];
#pragma unroll
        for (int m = 0; m < 9; m++) v[m] = pbX[m * 32 + t];
        rank9(v, r);
#pragma unroll
        for (int m = 0; m < 9; m++) {
            int kd = t * 9 + r[m];
            g_pBs[bfrag_idx(18, kb, kd)]       = f2bf(v[m] * v[m]);
            g_pBs[bfrag_idx(18, kb, 288 + kd)] = f2bf(v[m]);
        }
    }
}

// ---------------- kernel 2: pure P5 — stage per-b tables, MFMA, epilogue ----------------
struct M3 {
    u16   Cf[NBM][584];     // 16B-aligned stride (1168 B)
    u16   Cs[NBM][584];
    u16   hrootL[NBM][136];
    u16   hpoolb[NBM][136];
    float drad[NBM][65];
    float hbv[NBM][33];
    float sc[NBM][9];       // 1:hrn 2:alpha 3:t1x 4:t1s
};
__global__ __launch_bounds__(1024, 8) void k_main(
    const void* an_b1, const void* an_w2, const void* an_b2,
    const void* wn_b1, const void* wn_w2, const void* wn_b2,
    const void* alpha_raw, const void* w_raw, const void* log_gamma,
    const void* xlg, void* out, int B) {
    __shared__ __align__(16) M3 S;
    int t = threadIdx.x, lane = t & 63, w = t >> 6;
    const int f32 = (((const u16*)xlg)[0] == 0);
    int fm = lane & 15, quad = lane >> 4;
    int bw = blockIdx.x * NBM + w;
    bool bv = (bw < B);

    // ================= P0: coalesced stage of per-b tables =================
    if (bv) {
        {
            const short8* src = (const short8*)(g_Cf + (long)bw * 576);
            short8* dst = (short8*)S.Cf[w];
            for (int i = lane; i < 72; i += 64) dst[i] = src[i];
        }
        {
            const short8* src = (const short8*)(g_Cs + (long)bw * 576);
            short8* dst = (short8*)S.Cs[w];
            for (int i = lane; i < 72; i += 64) dst[i] = src[i];
        }
        if (lane < 16) {
            ((short8*)S.hrootL[w])[lane] = ((const short8*)(g_hroot + (long)bw * 128))[lane];
            ((short8*)S.hpoolb[w])[lane] = ((const short8*)(g_hpool + (long)bw * 128))[lane];
        }
        S.drad[w][lane] = g_drad[(long)bw * 64 + lane];
        if (lane == 0) {
            S.sc[w][1] = g_hrn[bw];
            S.sc[w][3] = g_t1x[bw];
            S.sc[w][4] = g_t1s[bw];
        }
    } else {
        short8 z = {0, 0, 0, 0, 0, 0, 0, 0};
        for (int i = lane; i < 72; i += 64) {
            ((short8*)S.Cf[w])[i] = z;
            ((short8*)S.Cs[w])[i] = z;
        }
        if (lane < 16) {
            ((short8*)S.hrootL[w])[lane] = z;
            ((short8*)S.hpoolb[w])[lane] = z;
        }
    }
    __syncthreads();   // SY1

    // ================= P5a: MFMA phase, wave-specialized =================
    f32x4 rd = {0.f, 0.f, 0.f, 0.f};
    f32x4 accF = {0.f, 0.f, 0.f, 0.f}, accS = {0.f, 0.f, 0.f, 0.f};
    if (w < 4) {
#pragma unroll
        for (int ks = 0; ks < 4; ks++) {
            short8 af = *(const short8*)(S.hrootL[fm] + ks * 32 + quad * 8);
            short8 bfr = *(const short8*)(g_pBr + ((w * 4 + ks) * 64 + lane) * 8);
            rd = MFMA(af, bfr, rd);
        }
#pragma unroll
        for (int ks = 0; ks < 18; ks++) {
            short8 aF = *(const short8*)(S.Cf[fm] + ks * 32 + quad * 8);
            short8 aS = *(const short8*)(S.Cs[fm] + ks * 32 + quad * 8);
            short8 bF = *(const short8*)(g_pBx + ((w * 18 + ks) * 64 + lane) * 8);
            short8 bS = *(const short8*)(g_pBs + ((w * 18 + ks) * 64 + lane) * 8);
            accF = MFMA(aF, bF, accF);
            accS = MFMA(aS, bS, accS);
        }
    } else if (w == 4) {
        f32x4 a0 = {0.f, 0.f, 0.f, 0.f}, a1 = {0.f, 0.f, 0.f, 0.f};
#pragma unroll
        for (int ks = 0; ks < 4; ks++) {
            short8 af = *(const short8*)(S.hrootL[fm] + ks * 32 + quad * 8);
            short8 b0 = *(const short8*)(g_pWn + ((0 * 4 + ks) * 64 + lane) * 8);
            short8 b1 = *(const short8*)(g_pWn + ((1 * 4 + ks) * 64 + lane) * 8);
            a0 = MFMA(af, b0, a0);
            a1 = MFMA(af, b1, a1);
        }
        float wb0 = ldv(wn_b1, fm, f32), wb1 = ldv(wn_b1, 16 + fm, f32);
#pragma unroll
        for (int reg = 0; reg < 4; reg++) {
            int b = quad * 4 + reg;
            S.hbv[b][fm]      = a0[reg] + wb0;
            S.hbv[b][16 + fm] = a1[reg] + wb1;
        }
    } else if (w == 5) {
        f32x4 a0 = {0.f, 0.f, 0.f, 0.f}, a1 = {0.f, 0.f, 0.f, 0.f};
#pragma unroll
        for (int ks = 0; ks < 4; ks++) {
            short8 af = *(const short8*)(S.hpoolb[fm] + ks * 32 + quad * 8);
            short8 b0 = *(const short8*)(g_pAn + ((0 * 4 + ks) * 64 + lane) * 8);
            short8 b1 = *(const short8*)(g_pAn + ((1 * 4 + ks) * 64 + lane) * 8);
            a0 = MFMA(af, b0, a0);
            a1 = MFMA(af, b1, a1);
        }
        float ab0 = ldv(an_b1, fm, f32), ab1 = ldv(an_b1, 16 + fm, f32);
        float aw0 = ldv(an_w2, fm, f32), aw1 = ldv(an_w2, 16 + fm, f32);
        float araw = ldv(alpha_raw, 0, f32), ab2 = ldv(an_b2, 0, f32);
#pragma unroll
        for (int reg = 0; reg < 4; reg++) {
            float s = fmaxf(a0[reg] + ab0, 0.f) * aw0 + fmaxf(a1[reg] + ab1, 0.f) * aw1;
            s += __shfl_xor(s, 1); s += __shfl_xor(s, 2);
            s += __shfl_xor(s, 4); s += __shfl_xor(s, 8);
            if (fm == 0) S.sc[quad * 4 + reg][2] = sigmoidf(araw + s + ab2);
        }
    }
    __syncthreads();   // SY2: hbv + alpha ready

    // ================= P5b: epilogue =================
    if (w < 4) {
        int k = w * 16 + fm;
        float wb2 = ldv(wn_b2, 0, f32);
        float wr  = ldv(w_raw, 0, f32);
        float gamma = expf(ldv(log_gamma, 0, f32));
        float hprnk = g_hprn[k];
        float wl[4] = {0.f, 0.f, 0.f, 0.f};
#pragma unroll 4
        for (int j = 0; j < 32; j++) {
            float hptv = g_hpt[j * 64 + k];
            float w2v = ldv(wn_w2, j, f32);
#pragma unroll
            for (int reg = 0; reg < 4; reg++)
                wl[reg] = fmaf(fmaxf(S.hbv[quad * 4 + reg][j] + hptv, 0.f), w2v, wl[reg]);
        }
#pragma unroll
        for (int reg = 0; reg < 4; reg++) {
            int b = quad * 4 + reg, bb = blockIdx.x * NBM + b;
            if (bb >= B) continue;
            float swf = (S.sc[b][3] + accF[reg]) * (1.f / 32.f);
            float sws = (S.sc[b][4] + accS[reg]) * (1.f / 32.f);
            float drfk = S.sc[b][1] + hprnk - 2.f * rd[reg];
            float wgt = sigmoidf(wr + wl[reg] + wb2);
            float dfeat = wgt * drfk + (1.f - wgt) * swf;
            float dstr  = wgt * S.drad[b][k] + (1.f - wgt) * sws;
            float al = S.sc[b][2];
            float dfgw = al * dfeat + (1.f - al) * dstr;
            if (!(dfgw == dfgw)) dfgw = 1e30f;
            float res = expf(-gamma * dfgw);
            if (f32) ((float*)out)[(long)bb * 64 + k] = res;
            else     ((u16*)out)[(long)bb * 64 + k] = f2bf(res);
        }
    }
}

extern "C" void kernel_launch(void* const* d_in, const int* in_sizes, int n_in,
                              void* d_out, int out_size, void* d_ws, size_t ws_size,
                              hipStream_t stream) {
    const void* adj  = d_in[0];
    const void* feat = d_in[1];
    const int*  idxs = (const int*)d_in[2];
    const void* xlw  = d_in[3];
    const void* xlb  = d_in[4];
    const void* xlg  = d_in[5];
    const void* xlbt = d_in[6];
    const void* slg  = d_in[7];
    const void* slb  = d_in[8];
    const void* thx  = d_in[9];
    const void* ths  = d_in[10];
    const void* araw = d_in[11];
    const void* anw1 = d_in[12];
    const void* anb1 = d_in[13];
    const void* anw2 = d_in[14];
    const void* anb2 = d_in[15];
    const void* wnw1 = d_in[16];
    const void* wnb1 = d_in[17];
    const void* wnw2 = d_in[18];
    const void* wnb2 = d_in[19];
    const void* wraw = d_in[20];
    const void* prt  = d_in[21];
    const void* prn  = d_in[22];
    const void* prad = d_in[23];
    const void* pdn  = d_in[24];
    const void* lgam = d_in[25];
    int B = in_sizes[2] / 10;
    int NBW = (B + 3) / 4;

    k_pack<<<3, 256, 0, stream>>>(xlw, thx, ths, anw1, wnw1, prad,
                                  xlb, xlg, xlbt, slg, slb);
    k_lin<<<NBP + NBW, 256, 0, stream>>>(adj, feat, idxs, prt, prn,
                                         xlb, xlg, xlbt, slg, slb, wnw1,
                                         pdn, B);
    k_main<<<(B + NBM - 1) / NBM, 1024, 0, stream>>>(
                                  anb1, anw2, anb2, wnb1, wnw2, wnb2,
                                  araw, wraw, lgam, xlg, d_out, B);
}

// Round 9
// 208.047 us; speedup vs baseline: 1.0499x; 1.0499x over previous
//
#include <hip/hip_runtime.h>
#include <hip/hip_bf16.h>

typedef unsigned short u16;
typedef __attribute__((ext_vector_type(8))) short short8;   // 8 bf16 (4 VGPRs)
typedef __attribute__((ext_vector_type(4))) float f32x4;

#define NN 9
#define DX 128
#define KP 64
#define LL 32
#define NALL 100000
#define BMAX 8192
#define NBM 16   // b's per k_main block (16 waves of 1024-thread block)
#define NBP 64   // proto blocks in k_lin, 1 prototype per block

#define MFMA(a, b, c) __builtin_amdgcn_mfma_f32_16x16x32_bf16(a, b, c, 0, 0, 0)
// intra-wave LDS phase fence: DS ops are in-order per wave; this stops compiler reordering
#define WFENCE() __threadfence_block()

// ---------- cross-kernel tables ----------
__device__ __align__(16) float g_tns[LL * NN];        // normalized theta_s [l][j]
__device__ __align__(16) float g_hprn[KP];            // ||h_proto_root||^2 [k]
__device__ __align__(16) float g_hpt[32 * KP];        // hp^T [j][k]
__device__ __align__(16) float g_rpst[NN * KP];       // sorted proto_rad [m][k]
__device__ __align__(16) u16   g_hx[BMAX * 10 * DX];  // batch LN'd h rows, bf16
// MFMA fragment-packed B tables (bf16)
__device__ __align__(16) u16   g_pW[16384];           // x_lin_w: K=128, N=128
__device__ __align__(16) u16   g_pBt[4096];           // tnx:  K=128, N=32
__device__ __align__(16) u16   g_pBr[8192];           // hprt: K=128, N=64
__device__ __align__(16) u16   g_pBx[36864];          // sw feat [pf^2|pf]: K=576, N=64
__device__ __align__(16) u16   g_pBs[36864];          // sw str  [qf^2|qf]: K=576, N=64
__device__ __align__(16) u16   g_pAn[4096];           // an_w1: K=128, N=32
__device__ __align__(16) u16   g_pWn[4096];           // wn_w1[:128]: K=128, N=32

__device__ __forceinline__ float bf2f(u16 u) {
    union { unsigned u; float f; } v; v.u = ((unsigned)u) << 16; return v.f;
}
__device__ __forceinline__ u16 f2bf(float f) {
    __hip_bfloat16 h = __float2bfloat16(f);
    union { __hip_bfloat16 h; u16 u; } v; v.h = h; return v.u;
}
__device__ __forceinline__ float ldv(const void* p, long i, int f32) {
    return f32 ? ((const float*)p)[i] : bf2f(((const u16*)p)[i]);
}
__device__ __forceinline__ float sigmoidf(float x) { return 1.f / (1.f + expf(-x)); }

__device__ __forceinline__ int bfrag_idx(int ksteps, int ncol, int kd) {
    int ntile = ncol >> 4, n = ncol & 15;
    int kstep = kd >> 5, quad = (kd >> 3) & 3, j = kd & 7;
    return ((ntile * ksteps + kstep) * 64 + quad * 16 + n) * 8 + j;
}

__device__ __forceinline__ void rank9(const float* v, int* r) {
#pragma unroll
    for (int m = 0; m < 9; m++) {
        int rk = 0;
#pragma unroll
        for (int n = 0; n < 9; n++)
            rk += (v[n] < v[m]) || (v[n] == v[m] && n < m);
        r[m] = rk;
    }
}

// ---------------- kernel 0: one-time packing ----------------
__global__ __launch_bounds__(256) void k_pack(
    const void* xlw, const void* theta_x, const void* theta_s,
    const void* an_w1, const void* wn_w1, const void* xlg) {
    int t = threadIdx.x;
    const int f32 = (((const u16*)xlg)[0] == 0);
    if (blockIdx.x == 0) {
        for (int i = t; i < 16384; i += 256) {
            int c = i >> 7, d = i & 127;
            g_pW[bfrag_idx(4, d, c)] = f2bf(ldv(xlw, i, f32));
        }
    } else if (blockIdx.x == 1) {
        if (t < 32) {
            float s = 0;
            for (int d = 0; d < 128; d++) { float v = ldv(theta_x, t * 128 + d, f32); s = fmaf(v, v, s); }
            float inv = 1.f / sqrtf(s);
            for (int d = 0; d < 128; d++)
                g_pBt[bfrag_idx(4, t, d)] = f2bf(ldv(theta_x, t * 128 + d, f32) * inv);
        } else if (t < 64) {
            int l = t - 32;
            float s = 0;
            for (int j = 0; j < 9; j++) { float v = ldv(theta_s, l * 9 + j, f32); s = fmaf(v, v, s); }
            float inv = 1.f / sqrtf(s);
            for (int j = 0; j < 9; j++) g_tns[l * 9 + j] = ldv(theta_s, l * 9 + j, f32) * inv;
        }
    } else {
        for (int i = t; i < 4096; i += 256) {
            int d = i >> 5, j = i & 31;
            g_pAn[bfrag_idx(4, j, d)] = f2bf(ldv(an_w1, i, f32));
            g_pWn[bfrag_idx(4, j, d)] = f2bf(ldv(wn_w1, i, f32));
        }
    }
}

// ---------------- kernel 1: lin+LN for all rows; proto blocks run proto chain ----------------
// g_pW staged into LDS via straight vector copy (pre-packed, no per-block repack math).
// launch_bounds(256,4): ~128-reg budget -> all 4 A-fragments + params live in registers.
__global__ __launch_bounds__(256, 4) void k_lin(
    const void* feat, const int* idxs,
    const void* proto_root, const void* proto_neigh,
    const void* xlb, const void* xlg, const void* xlbt,
    const void* slg, const void* slb, const void* wn_w1,
    const void* proto_rad, const void* proto_dn, int B) {
    __shared__ __align__(16) u16   WfL[16384];   // 32KB staged W fragments
    __shared__ __align__(16) u16   hXpb[1280];   // [10][128] bf16 (proto only)
    __shared__ __align__(16) float pbX[288];     // [9][32]
    __shared__ __align__(16) float Cm[84];       // [81]
    __shared__ __align__(16) float hsnP[84];     // [81]

    int t = threadIdx.x, lane = t & 63, w = t >> 6;
    const int f32 = (((const u16*)xlg)[0] == 0);
    int fm = lane & 15, quad = lane >> 4;
    bool isProto = (blockIdx.x < (unsigned)NBP);
    int rcap = isProto ? 10 : 60;
    int base = isProto ? blockIdx.x * 10 : (blockIdx.x - NBP) * 60;
    int rowT = isProto ? KP * 10 : B * 10;

    // ---- stage pre-packed W -> LDS (straight vector copy, L2-hot source) ----
    {
        const short8* src = (const short8*)g_pW;
        short8* dst = (short8*)WfL;
#pragma unroll
        for (int i = 0; i < 8; i++) dst[t + 256 * i] = src[t + 256 * i];
    }

    // ---- gather setup + issue A loads + preload params (overlaps staging) ----
    int lr = w * 16 + fm, gr = base + lr;
    bool azero = true;
    const void* abuf = feat; long aoff = 0;
    if (lr < rcap && gr < rowT) {
        if (!isProto) {
            int id = idxs[gr];
            if (id != NALL) { azero = false; aoff = (long)id * 128; }
        } else {
            int rr = gr % 10; azero = false;
            if (rr < 9) { abuf = proto_neigh; aoff = (long)((gr / 10) * 9 + rr) * 128; }
            else        { abuf = proto_root;  aoff = (long)(gr / 10) * 128; }
        }
    }
    short8 af[4];
#pragma unroll
    for (int ks = 0; ks < 4; ks++) af[ks] = (short8){0, 0, 0, 0, 0, 0, 0, 0};
    if (!azero) {
        if (f32) {
#pragma unroll
            for (int ks = 0; ks < 4; ks++) {
                const f32x4* src = (const f32x4*)((const float*)abuf + aoff + ks * 32 + quad * 8);
                f32x4 v0 = src[0], v1 = src[1];
                u16* ap = (u16*)&af[ks];
#pragma unroll
                for (int j = 0; j < 4; j++) { ap[j] = f2bf(v0[j]); ap[4 + j] = f2bf(v1[j]); }
            }
        } else {
#pragma unroll
            for (int ks = 0; ks < 4; ks++)
                af[ks] = *(const short8*)((const u16*)abuf + aoff + ks * 32 + quad * 8);
        }
    }
    float bias8[8], gg8[8], bb8[8];
#pragma unroll
    for (int nt = 0; nt < 8; nt++) {
        int col = nt * 16 + fm;
        bias8[nt] = ldv(xlb, col, f32);
        gg8[nt]   = ldv(xlg, col, f32);
        bb8[nt]   = ldv(xlbt, col, f32);
    }
    __syncthreads();   // WfL ready

    if (w * 16 < rcap) {
        f32x4 acc[8];
#pragma unroll
        for (int nt = 0; nt < 8; nt++) acc[nt] = (f32x4){0.f, 0.f, 0.f, 0.f};
#pragma unroll
        for (int ks = 0; ks < 4; ks++) {
#pragma unroll
            for (int nt = 0; nt < 8; nt++) {
                short8 bf = *(const short8*)(WfL + ((nt * 4 + ks) * 64 + lane) * 8);
                acc[nt] = MFMA(af[ks], bf, acc[nt]);
            }
        }
#pragma unroll
        for (int reg = 0; reg < 4; reg++) {
            float s = 0, q = 0;
#pragma unroll
            for (int nt = 0; nt < 8; nt++) {
                float v = acc[nt][reg] + bias8[nt];
                s += v; q = fmaf(v, v, q);
            }
#pragma unroll
            for (int m = 1; m < 16; m <<= 1) { s += __shfl_xor(s, m); q += __shfl_xor(q, m); }
            float mu = s * (1.f / 128.f);
            float var = fmaxf(q * (1.f / 128.f) - mu * mu, 0.f);
            float rs = rsqrtf(var + 1e-5f);
            int rowD = w * 16 + quad * 4 + reg, grD = base + rowD;
            if (rowD < rcap && grD < rowT) {
#pragma unroll
                for (int nt = 0; nt < 8; nt++) {
                    float val = (acc[nt][reg] + bias8[nt] - mu) * rs * gg8[nt] + bb8[nt];
                    if (!isProto) g_hx[grD * 128 + nt * 16 + fm] = f2bf(val);
                    else          hXpb[rowD * 128 + nt * 16 + fm] = f2bf(val);
                }
            }
        }
    }
    if (!isProto) return;

    // ================= proto chain (1 prototype per block) =================
    __syncthreads();
    int kb = blockIdx.x;

    for (int i = t; i < 128; i += 256)
        g_pBr[bfrag_idx(4, kb, i)] = hXpb[1152 + i];
    if (w == 0) {
        float v0 = bf2f(hXpb[1152 + lane]);
        float v1 = bf2f(hXpb[1216 + lane]);
        float q = v0 * v0 + v1 * v1;
#pragma unroll
        for (int m = 32; m >= 1; m >>= 1) q += __shfl_xor(q, m);
        if (lane == 0) g_hprn[kb] = q;
    }
    {   // hpt: 256 threads = 32 j's x 8 segments of 16 d's, shuffle-reduce
        int j = t >> 3, sub = t & 7;
        float a = 0;
#pragma unroll
        for (int dd = 0; dd < 16; dd++) {
            int d = sub * 16 + dd;
            a = fmaf(bf2f(hXpb[1152 + d]), ldv(wn_w1, (128 + d) * 32 + j, f32), a);
        }
        a += __shfl_xor(a, 1);
        a += __shfl_xor(a, 2);
        a += __shfl_xor(a, 4);
        if (sub == 0) g_hpt[j * 64 + kb] = a;
    }
    if (t == 0) {
        float v[9]; int r[9];
#pragma unroll
        for (int m = 0; m < 9; m++) v[m] = ldv(proto_rad, kb * 9 + m, f32);
        rank9(v, r);
#pragma unroll
        for (int m = 0; m < 9; m++) g_rpst[r[m] * 64 + kb] = v[m];
    }
    if (w == 0) {
        f32x4 acc0 = {0.f, 0.f, 0.f, 0.f}, acc1 = {0.f, 0.f, 0.f, 0.f};
        const u16* arow = hXpb + fm * 128;
#pragma unroll
        for (int ks = 0; ks < 4; ks++) {
            short8 afp = {0, 0, 0, 0, 0, 0, 0, 0};
            if (fm < 9) afp = *(const short8*)(arow + ks * 32 + quad * 8);
            short8 b0 = *(const short8*)(g_pBt + ((0 * 4 + ks) * 64 + lane) * 8);
            short8 b1 = *(const short8*)(g_pBt + ((1 * 4 + ks) * 64 + lane) * 8);
            acc0 = MFMA(afp, b0, acc0);
            acc1 = MFMA(afp, b1, acc1);
        }
#pragma unroll
        for (int reg = 0; reg < 4; reg++) {
            int row = quad * 4 + reg;
            if (row < 9) {
                pbX[row * 32 + fm]      = acc0[reg];
                pbX[row * 32 + 16 + fm] = acc1[reg];
            }
        }
    }
    for (int i = t; i < 81; i += 256) {
        int ii = i / 9, jj = i % 9; float v = 0.f;
        if (ii != jj) {
            int a = (ii < jj) ? ii : jj, b2 = (ii < jj) ? jj : ii;
            int p = a * 8 - a * (a - 1) / 2 + (b2 - a - 1);
            v = sigmoidf(ldv(proto_dn, p * 64 + kb, f32));
        }
        Cm[i] = v;
    }
    __syncthreads();
    if (t < 32) {
        float v[9]; int r[9];
#pragma unroll
        for (int m = 0; m < 9; m++) v[m] = pbX[m * 32 + t];
        rank9(v, r);
#pragma unroll
        for (int m = 0; m < 9; m++) {
            int kd = t * 9 + r[m];
            g_pBx[bfrag_idx(18, kb, kd)]       = f2bf(v[m] * v[m]);
            g_pBx[bfrag_idx(18, kb, 288 + kd)] = f2bf(v[m]);
        }
    }
    if (t >= 64 && t < 73) {
        int col = t - 64;
        float v[9]; int r[9];
#pragma unroll
        for (int j = 0; j < 9; j++) v[j] = Cm[j * 9 + col];
        rank9(v, r);
#pragma unroll
        for (int j = 0; j < 9; j++) Cm[r[j] * 9 + col] = v[j];
    }
    __syncthreads();
    if (t < 9) {
        float mu = 0;
#pragma unroll
        for (int j = 0; j < 9; j++) mu += Cm[t * 9 + j];
        mu *= (1.f / 9.f);
        float var = 0;
#pragma unroll
        for (int j = 0; j < 9; j++) { float d0 = Cm[t * 9 + j] - mu; var = fmaf(d0, d0, var); }
        var *= (1.f / 9.f);
        float rs = rsqrtf(var + 1e-5f);
#pragma unroll
        for (int j = 0; j < 9; j++)
            hsnP[t * 9 + j] = (Cm[t * 9 + j] - mu) * rs * ldv(slg, j, f32) + ldv(slb, j, f32);
    }
    __syncthreads();
    if (t < 32) {
#pragma unroll
        for (int m = 0; m < 9; m++) {
            float a = 0;
#pragma unroll
            for (int j = 0; j < 9; j++) a = fmaf(hsnP[m * 9 + j], g_tns[t * 9 + j], a);
            pbX[m * 32 + t] = a;
        }
    }
    __syncthreads();
    if (t < 32) {
        float v[9]; int r[9];
#pragma unroll
        for (int m = 0; m < 9; m++) v[m] = pbX[m * 32 + t];
        rank9(v, r);
#pragma unroll
        for (int m = 0; m < 9; m++) {
            int kd = t * 9 + r[m];
            g_pBs[bfrag_idx(18, kb, kd)]       = f2bf(v[m] * v[m]);
            g_pBs[bfrag_idx(18, kb, 288 + kd)] = f2bf(v[m]);
        }
    }
}

// ---------------- kernel 2: 16 b's per block (1024 thr), one wave per b ----------------
// P0..P4 are strictly intra-wave (own [w] LDS slice) -> no barriers, only WFENCE.
// P5 is cross-wave: 2 barriers. Strides padded for cross-b LDS access patterns.
struct M3 {
    u16   Cf[NBM][584];     // stride 1168B: %32 dwords == 4 -> spreads fm across banks
    u16   Cs[NBM][584];
    u16   hpoolb[NBM][136]; // bf16 pooled h, padded
    float pb[NBM][288];
    float df[NBM][100];
    float hst[NBM][81];     // LN'd in place (hsn)
    float drad[NBM][65];
    float hbv[NBM][33];
    float rbss[NBM][9], wrad[NBM][9];
    float sc[NBM][9];       // 1:hrn 2:alpha 3:t1x 4:t1s
};
__global__ __launch_bounds__(1024, 8) void k_main(
    const void* adj, const int* idxs,
    const void* slg, const void* slb,
    const void* an_b1, const void* an_w2, const void* an_b2,
    const void* wn_b1, const void* wn_w2, const void* wn_b2,
    const void* alpha_raw, const void* w_raw, const void* log_gamma,
    const void* xlg, void* out, int B) {
    __shared__ __align__(16) M3 S;
    int t = threadIdx.x, lane = t & 63, w = t >> 6;
    const int f32 = (((const u16*)xlg)[0] == 0);
    int fm = lane & 15, quad = lane >> 4;
    int bw = blockIdx.x * NBM + w;
    bool bv = (bw < B);

    unsigned long long mb = 0; float nv = 1e-9f, inv = 0.f;

    if (bv) {
        // ================= P0 =================
        bool valid = false;
        if (lane < 10) {
            int id = idxs[bw * 10 + lane];
            valid = (lane == 0) || (id != NALL);
        }
        mb = __ballot(valid);
        nv = (float)__popcll(mb & 0x3FEull) + 1e-9f;
        inv = 1.f / nv;
        unsigned rowbits = 0;
        if (lane < 10) {
            for (int j = 0; j < 10; j++)
                if (ldv(adj, (long)bw * 100 + lane * 10 + j, f32) > 1e-5f) rowbits |= 1u << j;
        }
        int dl[10];
#pragma unroll
        for (int j = 0; j < 10; j++) dl[j] = (j == lane) ? 0 : (((rowbits >> j) & 1) ? 1 : 10);
        unsigned reach = (lane < 10) ? (rowbits | (1u << lane)) : 0u;
        for (int s = 2; s <= 9; s++) {
            unsigned nr = reach;
#pragma unroll
            for (int j = 0; j < 10; j++) {
                unsigned rj = __shfl(rowbits, j);
                if ((reach >> j) & 1) nr |= rj;
            }
            unsigned add = nr & ~reach;
#pragma unroll
            for (int j = 0; j < 10; j++) if ((add >> j) & 1) dl[j] = s;
            reach = nr;
            if (__all(add == 0)) break;
        }
        if (lane < 10) {
            int mi = (int)((mb >> lane) & 1);
#pragma unroll
            for (int j = 0; j < 10; j++) {
                int mj = (int)((mb >> j) & 1);
                S.df[w][lane * 10 + j] = (mi && mj) ? (float)dl[j] * 0.1f : 1.0f;
            }
        }
        {   // row-0 distances: broadcast then 9-lane rank
            float v[9];
#pragma unroll
            for (int m = 0; m < 9; m++) {
                float vm = ((mb >> (1 + m)) & 1) ? (float)dl[1 + m] * 0.1f : 1.0f;
                v[m] = __shfl(vm, 0);
            }
            if (lane < 9) {
                float mine = v[0];
#pragma unroll
                for (int m = 1; m < 9; m++) if (lane == m) mine = v[m];
                int rk = 0;
#pragma unroll
                for (int n = 0; n < 9; n++) rk += (v[n] < mine) || (v[n] == mine && n < lane);
                S.rbss[w][rk] = mine;
                S.wrad[w][rk] = (((mb >> (1 + lane)) & 1) ? 1.f : 0.f) * inv;
            }
        }
        {
            u16 u0 = g_hx[bw * 1280 + lane], u1 = g_hx[bw * 1280 + 64 + lane];
            float v0 = bf2f(u0), v1 = bf2f(u1);
            float q = v0 * v0 + v1 * v1;
#pragma unroll
            for (int m = 32; m >= 1; m >>= 1) q += __shfl_xor(q, m);
            if (lane == 0) S.sc[w][1] = q;
        }
        for (int dd = lane; dd < 128; dd += 64) {
            float a = 0;
#pragma unroll
            for (int m = 0; m < 9; m++) {
                float hv = bf2f(g_hx[bw * 1280 + (1 + m) * 128 + dd]);
                float msk = ((mb >> (1 + m)) & 1) ? 1.f : 0.f;
                a = fmaf(hv, msk, a);
            }
            S.hpoolb[w][dd] = f2bf(a * inv);
        }
        {
            f32x4 acc0 = {0.f, 0.f, 0.f, 0.f}, acc1 = {0.f, 0.f, 0.f, 0.f};
            const u16* arow = g_hx + (bw * 10 + 1 + fm) * 128;
#pragma unroll
            for (int ks = 0; ks < 4; ks++) {
                short8 af = {0, 0, 0, 0, 0, 0, 0, 0};
                if (fm < 9) af = *(const short8*)(arow + ks * 32 + quad * 8);
                short8 b0 = *(const short8*)(g_pBt + ((0 * 4 + ks) * 64 + lane) * 8);
                short8 b1 = *(const short8*)(g_pBt + ((1 * 4 + ks) * 64 + lane) * 8);
                acc0 = MFMA(af, b0, acc0);
                acc1 = MFMA(af, b1, acc1);
            }
#pragma unroll
            for (int reg = 0; reg < 4; reg++) {
                int row = quad * 4 + reg;
                if (row < 9) {
                    S.pb[w][row * 32 + fm]      = acc0[reg];
                    S.pb[w][row * 32 + 16 + fm] = acc1[reg];
                }
            }
        }
        WFENCE();

        // ================= P1 =================
        {
            float t1 = 0;
            if (lane < 32) {
                float v[9]; int r[9];
#pragma unroll
                for (int m = 0; m < 9; m++) v[m] = S.pb[w][m * 32 + lane];
                rank9(v, r);
#pragma unroll
                for (int m = 0; m < 9; m++) {
                    float wgt = (((mb >> (1 + m)) & 1) ? 1.f : 0.f) * inv;
                    int slot = lane * 9 + r[m];
                    S.Cf[w][slot]       = f2bf(wgt);
                    S.Cf[w][288 + slot] = f2bf(-2.f * wgt * v[m]);
                    t1 = fmaf(wgt * v[m], v[m], t1);
                }
            }
#pragma unroll
            for (int m = 16; m >= 1; m >>= 1) t1 += __shfl_xor(t1, m);
            if (lane == 0) S.sc[w][3] = t1;
        }
        if (lane < 9) {
            float v[9]; int r[9];
#pragma unroll
            for (int i = 0; i < 9; i++) v[i] = S.df[w][(1 + i) * 10 + 1 + lane];
            rank9(v, r);
#pragma unroll
            for (int i = 0; i < 9; i++) S.hst[w][r[i] * 9 + lane] = v[i];
        }
        {
            float acc = 0;
#pragma unroll
            for (int m = 0; m < 9; m++) {
                float d0 = S.rbss[w][m] - g_rpst[m * 64 + lane];
                acc = fmaf(d0 * d0, S.wrad[w][m], acc);
            }
            S.drad[w][lane] = acc;
        }
        WFENCE();

        // ================= P2: LN rows of hst in place =================
        if (lane < 9) {
            float vv[9];
#pragma unroll
            for (int j = 0; j < 9; j++) vv[j] = S.hst[w][lane * 9 + j];
            float mu = 0;
#pragma unroll
            for (int j = 0; j < 9; j++) mu += vv[j];
            mu *= (1.f / 9.f);
            float var = 0;
#pragma unroll
            for (int j = 0; j < 9; j++) { float d0 = vv[j] - mu; var = fmaf(d0, d0, var); }
            var *= (1.f / 9.f);
            float rs = rsqrtf(var + 1e-5f);
#pragma unroll
            for (int j = 0; j < 9; j++)
                S.hst[w][lane * 9 + j] = (vv[j] - mu) * rs * ldv(slg, j, f32) + ldv(slb, j, f32);
        }
        WFENCE();

        // ================= P3: structural projections =================
        {
            int l = lane & 31;
            int m0 = (lane < 32) ? 0 : 5, m1 = (lane < 32) ? 5 : 9;
            for (int m = m0; m < m1; m++) {
                float a = 0;
#pragma unroll
                for (int j = 0; j < 9; j++) a = fmaf(S.hst[w][m * 9 + j], g_tns[l * 9 + j], a);
                S.pb[w][m * 32 + l] = a;
            }
        }
        WFENCE();

        // ================= P4 =================
        {
            float t1 = 0;
            if (lane < 32) {
                float v[9]; int r[9];
#pragma unroll
                for (int m = 0; m < 9; m++) v[m] = S.pb[w][m * 32 + lane];
                rank9(v, r);
#pragma unroll
                for (int m = 0; m < 9; m++) {
                    float wgt = (((mb >> (1 + m)) & 1) ? 1.f : 0.f) * inv;
                    int slot = lane * 9 + r[m];
                    S.Cs[w][slot]       = f2bf(wgt);
                    S.Cs[w][288 + slot] = f2bf(-2.f * wgt * v[m]);
                    t1 = fmaf(wgt * v[m], v[m], t1);
                }
            }
#pragma unroll
            for (int m = 16; m >= 1; m >>= 1) t1 += __shfl_xor(t1, m);
            if (lane == 0) S.sc[w][4] = t1;
        }
    }
    __syncthreads();   // SY1: cross-wave publish Cf/Cs/hpoolb/drad/sc

    // ================= P5a: MFMA phase, wave-specialized =================
    f32x4 rd = {0.f, 0.f, 0.f, 0.f};
    f32x4 accF = {0.f, 0.f, 0.f, 0.f}, accS = {0.f, 0.f, 0.f, 0.f};
    if (w < 4) {
#pragma unroll
        for (int ks = 0; ks < 4; ks++) {
            short8 af = {0, 0, 0, 0, 0, 0, 0, 0};
            int bb = blockIdx.x * NBM + fm;
            if (bb < B) af = *(const short8*)(g_hx + (long)bb * 1280 + ks * 32 + quad * 8);
            short8 bfr = *(const short8*)(g_pBr + ((w * 4 + ks) * 64 + lane) * 8);
            rd = MFMA(af, bfr, rd);
        }
#pragma unroll
        for (int ks = 0; ks < 18; ks++) {
            short8 aF = *(const short8*)(S.Cf[fm] + ks * 32 + quad * 8);
            short8 aS = *(const short8*)(S.Cs[fm] + ks * 32 + quad * 8);
            short8 bF = *(const short8*)(g_pBx + ((w * 18 + ks) * 64 + lane) * 8);
            short8 bS = *(const short8*)(g_pBs + ((w * 18 + ks) * 64 + lane) * 8);
            accF = MFMA(aF, bF, accF);
            accS = MFMA(aS, bS, accS);
        }
    } else if (w == 4) {
        // hb = hroot @ wn_w1[:128] + b1  -> S.hbv[b][j]
        f32x4 a0 = {0.f, 0.f, 0.f, 0.f}, a1 = {0.f, 0.f, 0.f, 0.f};
#pragma unroll
        for (int ks = 0; ks < 4; ks++) {
            short8 af = {0, 0, 0, 0, 0, 0, 0, 0};
            int bb = blockIdx.x * NBM + fm;
            if (bb < B) af = *(const short8*)(g_hx + (long)bb * 1280 + ks * 32 + quad * 8);
            short8 b0 = *(const short8*)(g_pWn + ((0 * 4 + ks) * 64 + lane) * 8);
            short8 b1 = *(const short8*)(g_pWn + ((1 * 4 + ks) * 64 + lane) * 8);
            a0 = MFMA(af, b0, a0);
            a1 = MFMA(af, b1, a1);
        }
        float wb0 = ldv(wn_b1, fm, f32), wb1 = ldv(wn_b1, 16 + fm, f32);
#pragma unroll
        for (int reg = 0; reg < 4; reg++) {
            int b = quad * 4 + reg;
            S.hbv[b][fm]      = a0[reg] + wb0;
            S.hbv[b][16 + fm] = a1[reg] + wb1;
        }
    } else if (w == 5) {
        // alpha = sigmoid(araw + relu(hpool @ an_w1 + b1) @ an_w2 + b2) -> S.sc[b][2]
        f32x4 a0 = {0.f, 0.f, 0.f, 0.f}, a1 = {0.f, 0.f, 0.f, 0.f};
#pragma unroll
        for (int ks = 0; ks < 4; ks++) {
            short8 af = *(const short8*)(S.hpoolb[fm] + ks * 32 + quad * 8);
            short8 b0 = *(const short8*)(g_pAn + ((0 * 4 + ks) * 64 + lane) * 8);
            short8 b1 = *(const short8*)(g_pAn + ((1 * 4 + ks) * 64 + lane) * 8);
            a0 = MFMA(af, b0, a0);
            a1 = MFMA(af, b1, a1);
        }
        float ab0 = ldv(an_b1, fm, f32), ab1 = ldv(an_b1, 16 + fm, f32);
        float aw0 = ldv(an_w2, fm, f32), aw1 = ldv(an_w2, 16 + fm, f32);
        float araw = ldv(alpha_raw, 0, f32), ab2 = ldv(an_b2, 0, f32);
#pragma unroll
        for (int reg = 0; reg < 4; reg++) {
            float s = fmaxf(a0[reg] + ab0, 0.f) * aw0 + fmaxf(a1[reg] + ab1, 0.f) * aw1;
            s += __shfl_xor(s, 1); s += __shfl_xor(s, 2);
            s += __shfl_xor(s, 4); s += __shfl_xor(s, 8);
            if (fm == 0) S.sc[quad * 4 + reg][2] = sigmoidf(araw + s + ab2);
        }
    }
    __syncthreads();   // SY2: hbv + alpha ready

    // ================= P5b: epilogue (waves 0-3; lane owns (b=quad*4+reg, k=w*16+fm)) ====
    if (w < 4) {
        int k = w * 16 + fm;
        float wb2 = ldv(wn_b2, 0, f32);
        float wr  = ldv(w_raw, 0, f32);
        float gamma = expf(ldv(log_gamma, 0, f32));
        float hprnk = g_hprn[k];
        float wl[4] = {0.f, 0.f, 0.f, 0.f};
#pragma unroll 4
        for (int j = 0; j < 32; j++) {
            float hptv = g_hpt[j * 64 + k];
            float w2v = ldv(wn_w2, j, f32);
#pragma unroll
            for (int reg = 0; reg < 4; reg++)
                wl[reg] = fmaf(fmaxf(S.hbv[quad * 4 + reg][j] + hptv, 0.f), w2v, wl[reg]);
        }
#pragma unroll
        for (int reg = 0; reg < 4; reg++) {
            int b = quad * 4 + reg, bb = blockIdx.x * NBM + b;
            if (bb >= B) continue;
            float swf = (S.sc[b][3] + accF[reg]) * (1.f / 32.f);
            float sws = (S.sc[b][4] + accS[reg]) * (1.f / 32.f);
            float drfk = S.sc[b][1] + hprnk - 2.f * rd[reg];
            float wgt = sigmoidf(wr + wl[reg] + wb2);
            float dfeat = wgt * drfk + (1.f - wgt) * swf;
            float dstr  = wgt * S.drad[b][k] + (1.f - wgt) * sws;
            float al = S.sc[b][2];
            float dfgw = al * dfeat + (1.f - al) * dstr;
            if (!(dfgw == dfgw)) dfgw = 1e30f;
            float res = expf(-gamma * dfgw);
            if (f32) ((float*)out)[(long)bb * 64 + k] = res;
            else     ((u16*)out)[(long)bb * 64 + k] = f2bf(res);
        }
    }
}

extern "C" void kernel_launch(void* const* d_in, const int* in_sizes, int n_in,
                              void* d_out, int out_size, void* d_ws, size_t ws_size,
                              hipStream_t stream) {
    const void* adj  = d_in[0];
    const void* feat = d_in[1];
    const int*  idxs = (const int*)d_in[2];
    const void* xlw  = d_in[3];
    const void* xlb  = d_in[4];
    const void* xlg  = d_in[5];
    const void* xlbt = d_in[6];
    const void* slg  = d_in[7];
    const void* slb  = d_in[8];
    const void* thx  = d_in[9];
    const void* ths  = d_in[10];
    const void* araw = d_in[11];
    const void* anw1 = d_in[12];
    const void* anb1 = d_in[13];
    const void* anw2 = d_in[14];
    const void* anb2 = d_in[15];
    const void* wnw1 = d_in[16];
    const void* wnb1 = d_in[17];
    const void* wnw2 = d_in[18];
    const void* wnb2 = d_in[19];
    const void* wraw = d_in[20];
    const void* prt  = d_in[21];
    const void* prn  = d_in[22];
    const void* prad = d_in[23];
    const void* pdn  = d_in[24];
    const void* lgam = d_in[25];
    int B = in_sizes[2] / 10;
    int NBQ = (B * 10 + 59) / 60;

    k_pack<<<3, 256, 0, stream>>>(xlw, thx, ths, anw1, wnw1, xlg);
    k_lin<<<NBP + NBQ, 256, 0, stream>>>(feat, idxs, prt, prn,
                                         xlb, xlg, xlbt, slg, slb, wnw1,
                                         prad, pdn, B);
    k_main<<<(B + NBM - 1) / NBM, 1024, 0, stream>>>(adj, idxs, slg, slb,
                                  anb1, anw2, anb2, wnb1, wnw2, wnb2,
                                  araw, wraw, lgam, xlg, d_out, B);
}